// Round 3
// baseline (121.823 us; speedup 1.0000x reference)
//
#include <hip/hip_runtime.h>
#include <hip/hip_cooperative_groups.h>
#include <math.h>

namespace cg = cooperative_groups;

#define K_CENTERS 512
#define T_TAB 8192
#define XMIN_T (-6.0f)
#define XMAX_T (6.0f)
#define H_TAB ((XMAX_T - XMIN_T) / (float)T_TAB)
#define INV_H ((float)T_TAB / (XMAX_T - XMIN_T))
#define SORT_BLOCKS 8
#define TAB_BLOCKS (((T_TAB + 1) * 8 + 255) / 256)   /* 257 */
#define GRID_BLOCKS 512                               /* == N/4/256 */

// One cooperative dispatch, two phases separated by grid.sync().
// Phase 1:
//   blocks 0..7          : rank-sort 512 centers (tie -> smaller orig index)
//                          pair[rank] = {value, (float)origIdx}
//   blocks 8..8+256      : softout/insertion table, 8 lanes per node:
//                          tab[n] = {softmax-mean(x_n), (float)#{k: c_k < x_n}}
//   remaining blocks     : idle into the sync
// Phase 2 (all 512 blocks, exactly N/4 threads):
//   table-interp softout; exact f32-faithful argmin via candidate scan of
//   value-sorted neighbors (replicates reference d=x-c, d2=d*d rounding and
//   first-min (smallest original index) tie-break).
//   Outputs (concat): zbar(=hardout), softout, hardout, symbols(as float).
__global__ __launch_bounds__(256, 2) void fused_quant_k(const float* __restrict__ data,
                                                        const float* __restrict__ centers,
                                                        float2* __restrict__ pair,
                                                        float2* __restrict__ tab,
                                                        float* __restrict__ out, int N) {
    __shared__ float2 lsP[K_CENTERS];
    int t = threadIdx.x;
    int b = blockIdx.x;

    // ---------------- phase 1 ----------------
    if (b < SORT_BLOCKS) {
        float* c = (float*)lsP;            // reuse LDS as 512-float scratch
        c[t] = centers[t];
        c[t + 256] = centers[t + 256];
        __syncthreads();
        int cidx = b * 64 + (t >> 2);      // 4 threads per center
        int p = t & 3;
        float x = c[cidx];
        int rank = 0;
        int j0 = p * 128;
#pragma unroll 8
        for (int i = 0; i < 128; ++i) {
            int j = j0 + i;
            float cj = c[j];
            rank += (cj < x || (cj == x && j < cidx)) ? 1 : 0;
        }
        rank += __shfl_xor(rank, 1);
        rank += __shfl_xor(rank, 2);
        if (p == 0) pair[rank] = make_float2(x, (float)cidx);
    } else if (b - SORT_BLOCKS < TAB_BLOCKS) {
        int gid = (b - SORT_BLOCKS) * 256 + t;
        int n = gid >> 3;
        int s = gid & 7;
        if (n <= T_TAB) {
            float xn = XMIN_T + (float)n * H_TAB;
            float w = 0.f, wc = 0.f;
            int ic = 0;
            int k0 = s * 64;
#pragma unroll 8
            for (int q = 0; q < 64; ++q) {
                float cv = centers[k0 + q];
                float d = xn - cv;
                float e = __expf(-d * d);          // SIGMA = 1
                w += e;
                wc = fmaf(e, cv, wc);
                ic += (cv < xn) ? 1 : 0;
            }
            w += __shfl_xor(w, 1); wc += __shfl_xor(wc, 1); ic += __shfl_xor(ic, 1);
            w += __shfl_xor(w, 2); wc += __shfl_xor(wc, 2); ic += __shfl_xor(ic, 2);
            w += __shfl_xor(w, 4); wc += __shfl_xor(wc, 4); ic += __shfl_xor(ic, 4);
            if (s == 0) tab[n] = make_float2(wc / w, (float)ic);
        }
    }

    __threadfence();            // make pair/tab visible device-wide
    cg::this_grid().sync();     // also a block barrier: safe to rewrite lsP

    // ---------------- phase 2 ----------------
    lsP[t] = pair[t];
    lsP[t + 256] = pair[t + 256];
    __syncthreads();

    int base = (b * 256 + t) * 4;
    if (base >= N) return;

    float4 xv = *reinterpret_cast<const float4*>(data + base);
    float xs[4] = {xv.x, xv.y, xv.z, xv.w};
    float zb[4], so[4], sy[4];

#pragma unroll
    for (int e = 0; e < 4; ++e) {
        float x = xs[e];
        // ---- softout via table interpolation ----
        float u = (x - XMIN_T) * INV_H;
        int i0 = (int)floorf(u);
        i0 = min(max(i0, 0), T_TAB - 1);
        float frac = u - (float)i0;
        frac = fminf(fmaxf(frac, 0.f), 1.f);
        float2 r0 = tab[i0];
        float2 r1 = tab[i0 + 1];
        so[e] = fmaf(frac, r1.x - r0.x, r0.x);
        // ---- exact argmin: scan sorted candidates around insertion point ----
        int jlo = max((int)r0.y - 3, 0);
        int jhi = min((int)r1.y + 2, K_CENTERS - 1);
        float bd2 = 3.4e38f;
        float bfo = 1.0e9f;     // original index as float (exact for <512)
        float bc = 0.f;
        for (int j = jlo; j <= jhi; ++j) {
            float2 P = lsP[j];
            float d = x - P.x;      // same rounding as reference
            float d2 = d * d;       // same rounding as reference
            bool better = (d2 < bd2) || ((d2 == bd2) && (P.y < bfo));
            if (better) { bd2 = d2; bfo = P.y; bc = P.x; }
        }
        zb[e] = bc;                 // zbar forward value == hardout
        sy[e] = bfo;
    }

    *reinterpret_cast<float4*>(out + base)         = make_float4(zb[0], zb[1], zb[2], zb[3]);
    *reinterpret_cast<float4*>(out + N + base)     = make_float4(so[0], so[1], so[2], so[3]);
    *reinterpret_cast<float4*>(out + 2 * N + base) = make_float4(zb[0], zb[1], zb[2], zb[3]);
    *reinterpret_cast<float4*>(out + 3 * N + base) = make_float4(sy[0], sy[1], sy[2], sy[3]);
}

extern "C" void kernel_launch(void* const* d_in, const int* in_sizes, int n_in,
                              void* d_out, int out_size, void* d_ws, size_t ws_size,
                              hipStream_t stream) {
    const float* data    = (const float*)d_in[0];
    const float* centers = (const float*)d_in[1];
    float* out = (float*)d_out;
    int N = in_sizes[0];   // 524288 == GRID_BLOCKS*256*4

    // ws layout (float2): [0,512) sorted {value, origIdx} | [512, 512+8193) table
    float2* pair = (float2*)d_ws;
    float2* tab  = pair + K_CENTERS;

    void* args[] = {(void*)&data, (void*)&centers, (void*)&pair, (void*)&tab,
                    (void*)&out, (void*)&N};
    hipLaunchCooperativeKernel((const void*)fused_quant_k,
                               dim3(GRID_BLOCKS), dim3(256), args, 0, stream);
}

// Round 4
// 18.094 us; speedup vs baseline: 6.7330x; 6.7330x over previous
//
#include <hip/hip_runtime.h>
#include <math.h>

#define K_CENTERS 512
#define T_TAB 4096
#define XMIN_T (-6.0f)
#define XMAX_T (6.0f)
#define H_TAB ((XMAX_T - XMIN_T) / (float)T_TAB)
#define INV_H ((float)T_TAB / (XMAX_T - XMIN_T))
#define SORT_BLOCKS 8
#define TAB_BLOCKS (((T_TAB + 1) * 8 + 255) / 256)   /* 129 */
#define WS_PAIRS 512
#define WS_TAB 4100                    /* 4097 used; padded so total is float4-divisible */
#define WS_TOTAL (WS_PAIRS + WS_TAB)   /* 4612 float2 = 2306 float4 = 36896 B */

// Setup dispatch (8 sort blocks + 129 table blocks).
// ws2[0..512)        = sorted {value, (float)origIdx}  (tie -> smaller orig index)
// ws2[512 + n]       = {softout(x_n), (float)#{k: c_k < x_n}},  n in [0..T_TAB]
__global__ __launch_bounds__(256) void setup_k(const float* __restrict__ centers,
                                               float2* __restrict__ ws2) {
    int t = threadIdx.x;
    int b = blockIdx.x;
    if (b < SORT_BLOCKS) {
        __shared__ alignas(16) float c[K_CENTERS];
        c[t] = centers[t];
        c[t + 256] = centers[t + 256];
        __syncthreads();
        int cidx = b * 64 + (t >> 2);      // 4 threads per center
        int p = t & 3;
        float x = c[cidx];
        const float4* c4 = reinterpret_cast<const float4*>(c);
        int q0 = p * 32;
        int rank = 0;
#pragma unroll 8
        for (int i = 0; i < 32; ++i) {
            float4 cj = c4[q0 + i];
            int j = (q0 + i) * 4;
            rank += (cj.x < x || (cj.x == x && (j + 0) < cidx)) ? 1 : 0;
            rank += (cj.y < x || (cj.y == x && (j + 1) < cidx)) ? 1 : 0;
            rank += (cj.z < x || (cj.z == x && (j + 2) < cidx)) ? 1 : 0;
            rank += (cj.w < x || (cj.w == x && (j + 3) < cidx)) ? 1 : 0;
        }
        rank += __shfl_xor(rank, 1);
        rank += __shfl_xor(rank, 2);
        if (p == 0) ws2[rank] = make_float2(x, (float)cidx);
    } else {
        int gid = (b - SORT_BLOCKS) * 256 + t;
        int n = gid >> 3;                  // 8 lanes per node
        int s = gid & 7;
        if (n > T_TAB) return;
        float xn = XMIN_T + (float)n * H_TAB;
        float w = 0.f, wc = 0.f;
        int ic = 0;
        int k0 = s * 64;
#pragma unroll 8
        for (int q = 0; q < 64; ++q) {
            float cv = centers[k0 + q];
            float d = xn - cv;
            float e = __expf(-d * d);      // SIGMA = 1
            w += e;
            wc = fmaf(e, cv, wc);
            ic += (cv < xn) ? 1 : 0;
        }
        w += __shfl_xor(w, 1); wc += __shfl_xor(wc, 1); ic += __shfl_xor(ic, 1);
        w += __shfl_xor(w, 2); wc += __shfl_xor(wc, 2); ic += __shfl_xor(ic, 2);
        w += __shfl_xor(w, 4); wc += __shfl_xor(wc, 4); ic += __shfl_xor(ic, 4);
        if (s == 0) ws2[WS_PAIRS + n] = make_float2(wc / w, (float)ic);
    }
}

// Main kernel: stage pairs+table in LDS (one contiguous 36.9KB copy, 10 float4
// loads/thread from L2), then per element: table-interp softout; exact
// f32-faithful argmin via candidate scan of value-sorted neighbors (replicates
// reference d=x-c, d2=d*d rounding and first-min tie-break on original index).
// Outputs (concat): zbar(=hardout), softout, hardout, symbols(as float).
__global__ __launch_bounds__(256) void quant_main_k(const float* __restrict__ data,
                                                    const float2* __restrict__ ws2,
                                                    float* __restrict__ out, int N) {
    __shared__ alignas(16) float2 buf[WS_TOTAL];
    int t = threadIdx.x;
    {
        const float4* src = reinterpret_cast<const float4*>(ws2);
        float4* dst = reinterpret_cast<float4*>(buf);
#pragma unroll
        for (int i = t; i < WS_TOTAL / 2; i += 256) dst[i] = src[i];
    }
    __syncthreads();
    const float2* lsP  = buf;              // sorted {value, origIdx}
    const float2* tabL = buf + WS_PAIRS;   // {F[n], Ins[n]}

    int base = (blockIdx.x * 256 + t) * 4;
    if (base >= N) return;

    float4 xv = *reinterpret_cast<const float4*>(data + base);
    float xs[4] = {xv.x, xv.y, xv.z, xv.w};
    float zb[4], so[4], sy[4];

#pragma unroll
    for (int e = 0; e < 4; ++e) {
        float x = xs[e];
        // ---- softout via table interpolation ----
        float u = (x - XMIN_T) * INV_H;
        int i0 = (int)floorf(u);
        i0 = min(max(i0, 0), T_TAB - 1);
        float frac = u - (float)i0;
        frac = fminf(fmaxf(frac, 0.f), 1.f);
        float2 r0 = tabL[i0];
        float2 r1 = tabL[i0 + 1];
        so[e] = fmaf(frac, r1.x - r0.x, r0.x);
        // ---- exact argmin: scan sorted candidates around insertion point ----
        int jlo = max((int)r0.y - 3, 0);
        int jhi = min((int)r1.y + 2, K_CENTERS - 1);
        float bd2 = 3.4e38f;
        float bfo = 1.0e9f;     // original index as float (exact for <512)
        float bc = 0.f;
        for (int j = jlo; j <= jhi; ++j) {
            float2 P = lsP[j];
            float d = x - P.x;      // same rounding as reference
            float d2 = d * d;       // same rounding as reference
            bool better = (d2 < bd2) || ((d2 == bd2) && (P.y < bfo));
            if (better) { bd2 = d2; bfo = P.y; bc = P.x; }
        }
        zb[e] = bc;                 // zbar forward value == hardout
        sy[e] = bfo;
    }

    *reinterpret_cast<float4*>(out + base)         = make_float4(zb[0], zb[1], zb[2], zb[3]);
    *reinterpret_cast<float4*>(out + N + base)     = make_float4(so[0], so[1], so[2], so[3]);
    *reinterpret_cast<float4*>(out + 2 * N + base) = make_float4(zb[0], zb[1], zb[2], zb[3]);
    *reinterpret_cast<float4*>(out + 3 * N + base) = make_float4(sy[0], sy[1], sy[2], sy[3]);
}

extern "C" void kernel_launch(void* const* d_in, const int* in_sizes, int n_in,
                              void* d_out, int out_size, void* d_ws, size_t ws_size,
                              hipStream_t stream) {
    const float* data    = (const float*)d_in[0];
    const float* centers = (const float*)d_in[1];
    float* out = (float*)d_out;
    int N = in_sizes[0];   // 524288

    float2* ws2 = (float2*)d_ws;   // [0,512) pairs | [512, 512+4100) table

    setup_k<<<SORT_BLOCKS + TAB_BLOCKS, 256, 0, stream>>>(centers, ws2);

    int mainBlocks = (N / 4 + 255) / 256;   // 512
    quant_main_k<<<mainBlocks, 256, 0, stream>>>(data, ws2, out, N);
}